// Round 1
// baseline (119.350 us; speedup 1.0000x reference)
//
#include <hip/hip_runtime.h>

#define EPS 1e-6f

__device__ __forceinline__ float elu1(float x) {
    // elu(x) + 1  ==  x > 0 ? x + 1 : exp(x)
    return x > 0.f ? x + 1.f : __expf(x);
}

// ---------------------------------------------------------------------------
// Phase 1: KVT[nh][d][m] = sum_s K'[s,d] * V[s,m];  Ksum[nh][d] = sum_s K'[s,d]
// Grid: (64 nh, 16 s-chunks), 256 threads. Each block covers 256 s-rows in
// 4 staged tiles of 64 rows. Thread tile: 4(m) x 4(d) outer-product acc.
// ---------------------------------------------------------------------------
__global__ __launch_bounds__(256) void kv_accum_kernel(
    const float* __restrict__ keys, const float* __restrict__ values,
    const float* __restrict__ mask, float* __restrict__ kvt,
    float* __restrict__ ksum)
{
    __shared__ float Ks[64][68];   // pad 68: 16B-aligned rows, bank stride 4
    __shared__ float Vs[64][68];

    const int nh = blockIdx.x;           // 0..63
    const int n = nh >> 4, h = nh & 15;
    const int t = threadIdx.x;
    const int mt = t >> 4, dt = t & 15;  // 16x16 thread grid over (m,d)
    const int m0 = mt * 4, d0 = dt * 4;

    float acc[4][4] = {{0.f, 0.f, 0.f, 0.f}, {0.f, 0.f, 0.f, 0.f},
                       {0.f, 0.f, 0.f, 0.f}, {0.f, 0.f, 0.f, 0.f}};
    float ksl = 0.f;                     // per-column K' sum (threads t<64)

    const int sbase = blockIdx.y * 256;

    for (int tile = 0; tile < 4; ++tile) {
        const int s0 = sbase + tile * 64;
        // stage 64 rows of K' (elu+mask) and V: 1024 float4 each, 4/thread
        #pragma unroll
        for (int k = 0; k < 4; ++k) {
            const int idx = t + k * 256;
            const int row = idx >> 4, seg = idx & 15;
            const int s = s0 + row;
            const size_t g = ((size_t)(n * 4096 + s) * 16 + h) * 64 + seg * 4;
            float4 k4 = *(const float4*)(keys + g);
            const float msk = mask[n * 4096 + s];
            k4.x = elu1(k4.x) * msk;
            k4.y = elu1(k4.y) * msk;
            k4.z = elu1(k4.z) * msk;
            k4.w = elu1(k4.w) * msk;
            *(float4*)&Ks[row][seg * 4] = k4;
            const float4 v4 = *(const float4*)(values + g);
            *(float4*)&Vs[row][seg * 4] = v4;
        }
        __syncthreads();
        // outer-product accumulate: per s, 2x ds_read_b128 -> 16 FMA
        #pragma unroll 8
        for (int s = 0; s < 64; ++s) {
            const float4 v4 = *(const float4*)&Vs[s][m0];
            const float4 k4 = *(const float4*)&Ks[s][d0];
            const float vv[4] = {v4.x, v4.y, v4.z, v4.w};
            const float kk[4] = {k4.x, k4.y, k4.z, k4.w};
            #pragma unroll
            for (int i = 0; i < 4; ++i)
                #pragma unroll
                for (int j = 0; j < 4; ++j)
                    acc[i][j] = fmaf(vv[i], kk[j], acc[i][j]);
        }
        // K' column sums (64 threads, conflict-free: consecutive addrs)
        if (t < 64) {
            #pragma unroll 8
            for (int s = 0; s < 64; ++s) ksl += Ks[s][t];
        }
        __syncthreads();
    }

    // accumulate into global (16-way contention across s-chunks)
    float* base = kvt + (size_t)nh * 4096;
    #pragma unroll
    for (int i = 0; i < 4; ++i)
        #pragma unroll
        for (int j = 0; j < 4; ++j)
            atomicAdd(base + (d0 + j) * 64 + (m0 + i), acc[i][j]);
    if (t < 64) atomicAdd(ksum + nh * 64 + t, ksl);
}

// ---------------------------------------------------------------------------
// Phase 2: out[n,l,h,m] = z_l * sum_d Q'[l,d] * KVT[d,m],
//          z_l = 1/(sum_d Q'[l,d]*Ksum[d] + EPS)
// Grid: (64 nh, 32 l-chunks of 128 rows), 256 threads.
// Thread tile: 4(l) x 8(m); per d: 3x ds_read_b128 -> 32 FMA.
// ---------------------------------------------------------------------------
__global__ __launch_bounds__(256) void out_kernel(
    const float* __restrict__ queries, const float* __restrict__ kvt,
    const float* __restrict__ ksum, float* __restrict__ out)
{
    __shared__ float QsT[64][132];  // [d][l], pad 132: float4-aligned, bank stride 4
    __shared__ float KVs[64][68];   // [d][m]
    __shared__ float Ksm[64];
    __shared__ float Zs[128];

    const int nh = blockIdx.x;
    const int n = nh >> 4, h = nh & 15;
    const int t = threadIdx.x;
    const int l0 = blockIdx.y * 128;

    // stage KVT (already [d][m] in global): 1024 float4, 4/thread
    #pragma unroll
    for (int k = 0; k < 4; ++k) {
        const int idx = t + k * 256;
        const int dd = idx >> 4, seg = idx & 15;
        const float4 v = *(const float4*)(kvt + (size_t)nh * 4096 + idx * 4);
        *(float4*)&KVs[dd][seg * 4] = v;
    }
    if (t < 64) Ksm[t] = ksum[nh * 64 + t];

    // stage Q' transposed into [d][l]: 2048 float4 reads, scalar LDS stores
    #pragma unroll
    for (int k = 0; k < 8; ++k) {
        const int idx = t + k * 256;
        const int row = idx >> 4, seg = idx & 15;
        const size_t g = ((size_t)(n * 4096 + l0 + row) * 16 + h) * 64 + seg * 4;
        float4 q4 = *(const float4*)(queries + g);
        q4.x = elu1(q4.x);
        q4.y = elu1(q4.y);
        q4.z = elu1(q4.z);
        q4.w = elu1(q4.w);
        QsT[seg * 4 + 0][row] = q4.x;
        QsT[seg * 4 + 1][row] = q4.y;
        QsT[seg * 4 + 2][row] = q4.z;
        QsT[seg * 4 + 3][row] = q4.w;
    }
    __syncthreads();

    // normalizers: one thread per row (128 rows)
    if (t < 128) {
        float a = 0.f;
        #pragma unroll 8
        for (int d = 0; d < 64; ++d) a = fmaf(QsT[d][t], Ksm[d], a);
        Zs[t] = 1.f / (a + EPS);
    }
    __syncthreads();

    // main GEMM: thread tile 4l x 8m
    const int mg = t & 7, lg = t >> 3;
    const int m0 = mg * 8, lt = lg * 4;
    float acc[4][8];
    #pragma unroll
    for (int i = 0; i < 4; ++i)
        #pragma unroll
        for (int j = 0; j < 8; ++j) acc[i][j] = 0.f;

    #pragma unroll 4
    for (int d = 0; d < 64; ++d) {
        const float4 q4 = *(const float4*)&QsT[d][lt];
        const float4 a4 = *(const float4*)&KVs[d][m0];
        const float4 b4 = *(const float4*)&KVs[d][m0 + 4];
        const float qq[4] = {q4.x, q4.y, q4.z, q4.w};
        const float mm[8] = {a4.x, a4.y, a4.z, a4.w, b4.x, b4.y, b4.z, b4.w};
        #pragma unroll
        for (int i = 0; i < 4; ++i)
            #pragma unroll
            for (int j = 0; j < 8; ++j)
                acc[i][j] = fmaf(qq[i], mm[j], acc[i][j]);
    }

    // scale by z and write out (2x float4 per row, coalesced across mg)
    #pragma unroll
    for (int i = 0; i < 4; ++i) {
        const float z = Zs[lt + i];
        const size_t g = ((size_t)(n * 4096 + l0 + lt + i) * 16 + h) * 64 + m0;
        float4 o;
        o.x = acc[i][0] * z; o.y = acc[i][1] * z;
        o.z = acc[i][2] * z; o.w = acc[i][3] * z;
        *(float4*)(out + g) = o;
        o.x = acc[i][4] * z; o.y = acc[i][5] * z;
        o.z = acc[i][6] * z; o.w = acc[i][7] * z;
        *(float4*)(out + g + 4) = o;
    }
}

extern "C" void kernel_launch(void* const* d_in, const int* in_sizes, int n_in,
                              void* d_out, int out_size, void* d_ws, size_t ws_size,
                              hipStream_t stream) {
    const float* queries = (const float*)d_in[0];
    const float* keys    = (const float*)d_in[1];
    const float* values  = (const float*)d_in[2];
    const float* mask    = (const float*)d_in[3];
    float* out  = (float*)d_out;
    float* kvt  = (float*)d_ws;                 // [64][64][64]  (nh, d, m)
    float* ksum = kvt + (size_t)64 * 4096;      // [64][64]

    // zero accumulators every call (deterministic; harness doesn't re-poison)
    hipMemsetAsync(d_ws, 0, (64 * 4096 + 64 * 64) * sizeof(float), stream);

    kv_accum_kernel<<<dim3(64, 16), 256, 0, stream>>>(keys, values, mask, kvt, ksum);
    out_kernel<<<dim3(64, 32), 256, 0, stream>>>(queries, kvt, ksum, out);
}